// Round 2
// baseline (609.077 us; speedup 1.0000x reference)
//
#include <hip/hip_runtime.h>

// VectorAttention: B=4, C=32, H=256, W=256, HID=64, all fp32.
// d_in: x, Wqkv, W1, b1, ln_w, ln_b, W2, b2, Wg, bg
//
// Algebra: hid_n = W1@(q - k_n) + b1 = (Wq1@x + b1) - (Wk1@x)|neighbor
//   Wq1 = W1 @ Wqkv[0:32,:], Wk1 = W1 @ Wqkv[32:64,:]  (64x32 each)
// ws layout (floats):
//   [0,2048)        Wq1   (row-major, [d][c])
//   [2048,4096)     Wk1
//   [4096,6144)     W2T   ([d][c], W2T[d*32+c] = W2[c*64+d])
//   [6144, +16777216)      kh (B,64,H,W) channel-major
//   [16783360, +8388608)   v  (B,32,H,W) channel-major

#define HWm 65536
#define NPIX 262144

// ---------------- kernel 0: tiny weight prep (1 block) ----------------
__global__ __launch_bounds__(256) void prep_kernel(
    const float* __restrict__ Wqkv, const float* __restrict__ W1,
    const float* __restrict__ W2, float* __restrict__ Wq1,
    float* __restrict__ Wk1, float* __restrict__ W2T)
{
    const int tid = threadIdx.x;
    // Wq1/Wk1: 2048 elems each; thread handles 8 of each
    for (int i = tid; i < 2048; i += 256) {
        const int d = i >> 5, c = i & 31;
        float aq = 0.f, ak = 0.f;
#pragma unroll
        for (int k = 0; k < 32; ++k) {
            const float w1 = W1[d * 32 + k];
            aq = fmaf(w1, Wqkv[k * 32 + c], aq);          // q rows 0..31
            ak = fmaf(w1, Wqkv[(32 + k) * 32 + c], ak);   // k rows 32..63
        }
        Wq1[i] = aq;
        Wk1[i] = ak;
        W2T[i] = W2[c * 64 + d];
    }
}

// ---------------- kernel 1: kh, v, base+residual ----------------
__global__ __launch_bounds__(256) void proj_kernel(
    const float* __restrict__ x, const float* __restrict__ Wqkv,
    const float* __restrict__ Wk1, const float* __restrict__ Wg,
    const float* __restrict__ bg, float* __restrict__ kh,
    float* __restrict__ v, float* __restrict__ out)
{
    const int pix = blockIdx.x * 256 + threadIdx.x;
    const int b = pix >> 16;
    const int rem = pix & 65535;

    const float* xp = x + b * (32 * HWm) + rem;
    float xv[32];
#pragma unroll
    for (int c = 0; c < 32; ++c) xv[c] = xp[c * HWm];

    // kh = Wk1 @ x  (64 outputs)
    float* khp = kh + b * (64 * HWm) + rem;
    for (int d = 0; d < 64; ++d) {
        float acc = 0.f;
        const float* wr = Wk1 + d * 32;
#pragma unroll
        for (int c = 0; c < 32; ++c) acc = fmaf(wr[c], xv[c], acc);
        khp[d * HWm] = acc;
    }

    // v = Wqkv[64:96] @ x  (32 outputs)
    float* vp = v + b * (32 * HWm) + rem;
    for (int o = 0; o < 32; ++o) {
        float acc = 0.f;
        const float* wr = Wqkv + (64 + o) * 32;
#pragma unroll
        for (int c = 0; c < 32; ++c) acc = fmaf(wr[c], xv[c], acc);
        vp[o * HWm] = acc;
    }

    // out = Wg @ x + bg + x
    float* outp = out + b * (32 * HWm) + rem;
    for (int o = 0; o < 32; ++o) {
        float acc = bg[o];
        const float* wr = Wg + o * 32;
#pragma unroll
        for (int c = 0; c < 32; ++c) acc = fmaf(wr[c], xv[c], acc);
        outp[o * HWm] = acc + xv[o];
    }
}

// ---------------- kernel 2: neighborhood attention, register-resident ----------------
__global__ __launch_bounds__(256, 2) void attn_kernel(
    const float* __restrict__ x, const float* __restrict__ Wq1,
    const float* __restrict__ b1, const float* __restrict__ lnw,
    const float* __restrict__ lnb, const float* __restrict__ W2T,
    const float* __restrict__ b2, const float* __restrict__ kh,
    const float* __restrict__ v, float* __restrict__ out)
{
    const int tid = threadIdx.x;
    const int pix = blockIdx.x * 256 + tid;
    const int b = pix >> 16;
    const int rem = pix & 65535;
    const int h = rem >> 8;
    const int w = rem & 255;

    // qh = Wq1 @ x + b1 (recomputed: cheaper than materializing 64ch)
    float qh[64];
    {
        const float* xp = x + b * (32 * HWm) + rem;
        float xv[32];
#pragma unroll
        for (int c = 0; c < 32; ++c) xv[c] = xp[c * HWm];
#pragma unroll 8
        for (int d = 0; d < 64; ++d) {
            float acc = b1[d];
            const float* wr = Wq1 + d * 32;
#pragma unroll
            for (int c = 0; c < 32; ++c) acc = fmaf(wr[c], xv[c], acc);
            qh[d] = acc;
        }
    }

    const float* khbase = kh + b * (64 * HWm);
    const float* vbase  = v + b * (32 * HWm);

    float ssum[32], wv[32];
#pragma unroll
    for (int c = 0; c < 32; ++c) { ssum[c] = 0.f; wv[c] = 0.f; }

    for (int n = 0; n < 9; ++n) {
        const int dy = n / 3 - 1, dx = n % 3 - 1;
        const int hh = h + dy, ww = w + dx;
        const bool valid = ((unsigned)hh < 256u) && ((unsigned)ww < 256u);
        const int noff = valid ? (hh * 256 + ww) : 0;

        // load neighbor kh (zero for padded neighbor)
        float khv[64];
#pragma unroll
        for (int d = 0; d < 64; ++d) {
            float kv = khbase[d * HWm + noff];
            khv[d] = valid ? kv : 0.f;
        }

        // LayerNorm stats of hid = qh - khv
        float sum = 0.f, sumsq = 0.f;
#pragma unroll
        for (int d = 0; d < 64; ++d) {
            const float hv = qh[d] - khv[d];
            sum += hv;
            sumsq = fmaf(hv, hv, sumsq);
        }
        const float mean = sum * (1.f / 64.f);
        float var = sumsq * (1.f / 64.f) - mean * mean;
        var = fmaxf(var, 0.f);
        const float inv = 1.f / (sqrtf(var) + 1e-5f);

        // scores = W2 @ relu(LN(hid)) + b2
        float sc[32];
#pragma unroll
        for (int c = 0; c < 32; ++c) sc[c] = b2[c];
#pragma unroll 8
        for (int d = 0; d < 64; ++d) {
            float hn = (qh[d] - khv[d] - mean) * inv;
            hn = fmaf(hn, lnw[d], lnb[d]);
            hn = fmaxf(hn, 0.f);
            const float* w2r = W2T + d * 32;
#pragma unroll
            for (int c = 0; c < 32; ++c) sc[c] = fmaf(w2r[c], hn, sc[c]);
        }

        // online softmax accumulation (|score| bounded ~4 by LN; no max needed)
#pragma unroll
        for (int c = 0; c < 32; ++c) {
            const float e = __expf(sc[c]);
            float vv = vbase[c * HWm + noff];
            vv = valid ? vv : 0.f;
            ssum[c] += e;
            wv[c] = fmaf(e, vv, wv[c]);
        }
    }

    float* outp = out + b * (32 * HWm) + rem;
#pragma unroll
    for (int c = 0; c < 32; ++c) {
        outp[c * HWm] += wv[c] / ssum[c];
    }
}

extern "C" void kernel_launch(void* const* d_in, const int* in_sizes, int n_in,
                              void* d_out, int out_size, void* d_ws, size_t ws_size,
                              hipStream_t stream) {
    const float* x    = (const float*)d_in[0];
    const float* Wqkv = (const float*)d_in[1];
    const float* W1   = (const float*)d_in[2];
    const float* b1   = (const float*)d_in[3];
    const float* lnw  = (const float*)d_in[4];
    const float* lnb  = (const float*)d_in[5];
    const float* W2   = (const float*)d_in[6];
    const float* b2   = (const float*)d_in[7];
    const float* Wg   = (const float*)d_in[8];
    const float* bg   = (const float*)d_in[9];
    float* out = (float*)d_out;

    float* ws  = (float*)d_ws;
    float* Wq1 = ws;                 // 2048
    float* Wk1 = ws + 2048;          // 2048
    float* W2T = ws + 4096;          // 2048
    float* kh  = ws + 6144;          // 16,777,216
    float* v   = kh + 16777216;      // 8,388,608

    const int nblocks = NPIX / 256;  // 1024
    prep_kernel<<<1, 256, 0, stream>>>(Wqkv, W1, W2, Wq1, Wk1, W2T);
    proj_kernel<<<nblocks, 256, 0, stream>>>(x, Wqkv, Wk1, Wg, bg, kh, v, out);
    attn_kernel<<<nblocks, 256, 0, stream>>>(x, Wq1, b1, lnw, lnb, W2T, b2, kh, v, out);
}

// Round 3
// 555.977 us; speedup vs baseline: 1.0955x; 1.0955x over previous
//
#include <hip/hip_runtime.h>

// VectorAttention: B=4, C=32, H=256, W=256, HID=64, all fp32.
// d_in: x, Wqkv, W1, b1, ln_w, ln_b, W2, b2, Wg, bg
//
// Algebra: hid_n = W1@(q - k_n) + b1 = (Wq1@x + b1) - (Wk1@x)|neighbor
//   Wq1 = W1 @ Wqkv[0:32,:], Wk1 = W1 @ Wqkv[32:64,:]  (64x32 each)
//
// ws layout (floats):
//   [0,2048)      Wq1  (row-major [d][c])
//   [2048,4096)   Wk1
//   [4096,6144)   W2T  ([d][c], W2T[d*32+c] = W2[c*64+d])
//   [6144, +16777216)    kh : PIXEL-major (B*H*W, 64)  -> 256B per pixel
//   [.., +8388608)       v  : PIXEL-major (B*H*W, 32)  -> 128B per pixel

#define HWm 65536
#define NPIX 262144

// ---------------- kernel 0: tiny weight prep (1 block) ----------------
__global__ __launch_bounds__(256) void prep_kernel(
    const float* __restrict__ Wqkv, const float* __restrict__ W1,
    const float* __restrict__ W2, float* __restrict__ Wq1,
    float* __restrict__ Wk1, float* __restrict__ W2T)
{
    const int tid = threadIdx.x;
    for (int i = tid; i < 2048; i += 256) {
        const int d = i >> 5, c = i & 31;
        float aq = 0.f, ak = 0.f;
#pragma unroll
        for (int k = 0; k < 32; ++k) {
            const float w1 = W1[d * 32 + k];
            aq = fmaf(w1, Wqkv[k * 32 + c], aq);
            ak = fmaf(w1, Wqkv[(32 + k) * 32 + c], ak);
        }
        Wq1[i] = aq;
        Wk1[i] = ak;
        W2T[i] = W2[c * 64 + d];
    }
}

// ---------------- kernel 1: kh (64ch) + v (32ch), PIXEL-major ----------------
__global__ __launch_bounds__(256) void kv_kernel(
    const float* __restrict__ x, const float* __restrict__ Wqkv,
    const float* __restrict__ Wk1, float* __restrict__ kh,
    float* __restrict__ v)
{
    const int pix = blockIdx.x * 256 + threadIdx.x;
    const int b = pix >> 16;
    const int rem = pix & 65535;

    const float* xp = x + b * (32 * HWm) + rem;
    float xv[32];
#pragma unroll
    for (int c = 0; c < 32; ++c) xv[c] = xp[c * HWm];

    // kh = Wk1 @ x, store pixel-major as float4s
    float4* khp = (float4*)(kh + (size_t)pix * 64);
#pragma unroll 4
    for (int i = 0; i < 16; ++i) {
        float a[4];
#pragma unroll
        for (int j = 0; j < 4; ++j) {
            const float* wr = Wk1 + (i * 4 + j) * 32;
            float acc = 0.f;
#pragma unroll
            for (int c = 0; c < 32; ++c) acc = fmaf(wr[c], xv[c], acc);
            a[j] = acc;
        }
        khp[i] = make_float4(a[0], a[1], a[2], a[3]);
    }

    // v = Wqkv[64:96] @ x, pixel-major
    float4* vp = (float4*)(v + (size_t)pix * 32);
#pragma unroll 4
    for (int i = 0; i < 8; ++i) {
        float a[4];
#pragma unroll
        for (int j = 0; j < 4; ++j) {
            const float* wr = Wqkv + (64 + i * 4 + j) * 32;
            float acc = 0.f;
#pragma unroll
            for (int c = 0; c < 32; ++c) acc = fmaf(wr[c], xv[c], acc);
            a[j] = acc;
        }
        vp[i] = make_float4(a[0], a[1], a[2], a[3]);
    }
}

// ---------------- kernel 2: fused attention + gate + residual ----------------
__global__ __launch_bounds__(256, 2) void attn_kernel(
    const float* __restrict__ x, const float* __restrict__ Wq1,
    const float* __restrict__ b1, const float* __restrict__ lnw,
    const float* __restrict__ lnb, const float* __restrict__ W2T,
    const float* __restrict__ b2, const float* __restrict__ Wg,
    const float* __restrict__ bg, const float* __restrict__ kh,
    const float* __restrict__ v, float* __restrict__ out)
{
    const int tid = threadIdx.x;
    // XCD-aware swizzle: 1024 blocks, 8 XCDs -> each XCD owns 128 contiguous rows
    const int bid = blockIdx.x;
    const int swz = (bid & 7) * 128 + (bid >> 3);
    const int pix = swz * 256 + tid;
    const int b = pix >> 16;
    const int rem = pix & 65535;
    const int h = rem >> 8;
    const int w = rem & 255;

    // qh = Wq1 @ x + b1
    float qh[64];
    {
        const float* xp = x + b * (32 * HWm) + rem;
        float xv[32];
#pragma unroll
        for (int c = 0; c < 32; ++c) xv[c] = xp[c * HWm];
#pragma unroll 8
        for (int d = 0; d < 64; ++d) {
            float acc = b1[d];
            const float* wr = Wq1 + d * 32;
#pragma unroll
            for (int c = 0; c < 32; ++c) acc = fmaf(wr[c], xv[c], acc);
            qh[d] = acc;
        }
    }

    float ssum[32], wv[32];
#pragma unroll
    for (int c = 0; c < 32; ++c) { ssum[c] = 0.f; wv[c] = 0.f; }

    const int bbase = b << 16;

    for (int n = 0; n < 9; ++n) {
        const int dy = n / 3 - 1, dx = n % 3 - 1;
        const int hh = h + dy, ww = w + dx;
        const bool valid = ((unsigned)hh < 256u) && ((unsigned)ww < 256u);
        const int noff = valid ? (hh * 256 + ww) : 0;
        const int npix = bbase + noff;

        // hid = qh - kh_n (pixel-major vector loads), zero-padded neighbor
        float hid[64];
        {
            const float4* khp = (const float4*)(kh + (size_t)npix * 64);
#pragma unroll
            for (int i = 0; i < 16; ++i) {
                const float4 kv = khp[i];
                hid[i * 4 + 0] = qh[i * 4 + 0] - (valid ? kv.x : 0.f);
                hid[i * 4 + 1] = qh[i * 4 + 1] - (valid ? kv.y : 0.f);
                hid[i * 4 + 2] = qh[i * 4 + 2] - (valid ? kv.z : 0.f);
                hid[i * 4 + 3] = qh[i * 4 + 3] - (valid ? kv.w : 0.f);
            }
        }

        // LayerNorm stats (biased var; denom = std + eps)
        float sum = 0.f, sumsq = 0.f;
#pragma unroll
        for (int d = 0; d < 64; ++d) {
            sum += hid[d];
            sumsq = fmaf(hid[d], hid[d], sumsq);
        }
        const float mean = sum * (1.f / 64.f);
        float var = sumsq * (1.f / 64.f) - mean * mean;
        var = fmaxf(var, 0.f);
        const float inv = 1.f / (sqrtf(var) + 1e-5f);

        // scores = W2 @ relu(LN(hid)) + b2
        float sc[32];
#pragma unroll
        for (int c = 0; c < 32; ++c) sc[c] = b2[c];
#pragma unroll 8
        for (int d = 0; d < 64; ++d) {
            float hn = (hid[d] - mean) * inv;
            hn = fmaf(hn, lnw[d], lnb[d]);
            hn = fmaxf(hn, 0.f);
            const float* w2r = W2T + d * 32;
#pragma unroll
            for (int c = 0; c < 32; ++c) sc[c] = fmaf(w2r[c], hn, sc[c]);
        }

        // online softmax accumulation (|score| bounded ~4 by LN)
        const float4* vp = (const float4*)(v + (size_t)npix * 32);
#pragma unroll
        for (int i = 0; i < 8; ++i) {
            float4 vv = vp[i];
            if (!valid) vv = make_float4(0.f, 0.f, 0.f, 0.f);
            const float e0 = __expf(sc[i * 4 + 0]);
            const float e1 = __expf(sc[i * 4 + 1]);
            const float e2 = __expf(sc[i * 4 + 2]);
            const float e3 = __expf(sc[i * 4 + 3]);
            ssum[i * 4 + 0] += e0; wv[i * 4 + 0] = fmaf(e0, vv.x, wv[i * 4 + 0]);
            ssum[i * 4 + 1] += e1; wv[i * 4 + 1] = fmaf(e1, vv.y, wv[i * 4 + 1]);
            ssum[i * 4 + 2] += e2; wv[i * 4 + 2] = fmaf(e2, vv.z, wv[i * 4 + 2]);
            ssum[i * 4 + 3] += e3; wv[i * 4 + 3] = fmaf(e3, vv.w, wv[i * 4 + 3]);
        }
    }

    // gate + residual recomputed here (x likely L2-hot), pure coalesced store
    {
        const float* xp = x + b * (32 * HWm) + rem;
        float xv[32];
#pragma unroll
        for (int c = 0; c < 32; ++c) xv[c] = xp[c * HWm];
        float* outp = out + b * (32 * HWm) + rem;
#pragma unroll 4
        for (int c = 0; c < 32; ++c) {
            float acc = bg[c];
            const float* wr = Wg + c * 32;
#pragma unroll
            for (int k = 0; k < 32; ++k) acc = fmaf(wr[k], xv[k], acc);
            outp[c * HWm] = acc + xv[c] + wv[c] / ssum[c];
        }
    }
}

extern "C" void kernel_launch(void* const* d_in, const int* in_sizes, int n_in,
                              void* d_out, int out_size, void* d_ws, size_t ws_size,
                              hipStream_t stream) {
    const float* x    = (const float*)d_in[0];
    const float* Wqkv = (const float*)d_in[1];
    const float* W1   = (const float*)d_in[2];
    const float* b1   = (const float*)d_in[3];
    const float* lnw  = (const float*)d_in[4];
    const float* lnb  = (const float*)d_in[5];
    const float* W2   = (const float*)d_in[6];
    const float* b2   = (const float*)d_in[7];
    const float* Wg   = (const float*)d_in[8];
    const float* bg   = (const float*)d_in[9];
    float* out = (float*)d_out;

    float* ws  = (float*)d_ws;
    float* Wq1 = ws;                 // 2048
    float* Wk1 = ws + 2048;          // 2048
    float* W2T = ws + 4096;          // 2048
    float* kh  = ws + 6144;          // 16,777,216 (pixel-major, 64/pixel)
    float* v   = kh + 16777216;      // 8,388,608  (pixel-major, 32/pixel)

    const int nblocks = NPIX / 256;  // 1024
    prep_kernel<<<1, 256, 0, stream>>>(Wqkv, W1, W2, Wq1, Wk1, W2T);
    kv_kernel<<<nblocks, 256, 0, stream>>>(x, Wqkv, Wk1, kh, v);
    attn_kernel<<<nblocks, 256, 0, stream>>>(x, Wq1, b1, lnw, lnb, W2T, b2,
                                             Wg, bg, kh, v, out);
}

// Round 4
// 338.370 us; speedup vs baseline: 1.8000x; 1.6431x over previous
//
#include <hip/hip_runtime.h>

// VectorAttention: B=4, C=32, H=256, W=256, HID=64, all fp32 in/out.
// Algebra: hid_n = (Wq1@x + b1) - (Wk1@x)|neighbor,  Wq1=W1@Wqkv_q, Wk1=W1@Wqkv_k
// Structure:
//   prep: Wq1, Wk1, W2T (f32, ws)
//   kv:   qh(64ch,bf16), kh(64ch,bf16), v(32ch,bf16) pixel-major; out = Wg@x+bg+x
//   attn: 16x16 tile/block, 18x18 halo of kh/v staged in LDS; out += attention
//
// ws (bytes): [0,8K) Wq1 | [8K,16K) Wk1 | [16K,24K) W2T
//             [24576, +33.5M) kh bf16 | +33.5M qh bf16 | +16.8M v bf16

#define HWm 65536
#define NPIX 262144

__device__ __forceinline__ float bflo(unsigned u) { return __uint_as_float(u << 16); }
__device__ __forceinline__ float bfhi(unsigned u) { return __uint_as_float(u & 0xFFFF0000u); }
__device__ __forceinline__ unsigned packbf2(float a, float b) {
    unsigned ua = __float_as_uint(a);
    unsigned ub = __float_as_uint(b);
    ua = (ua + 0x7FFFu + ((ua >> 16) & 1u)) >> 16;          // RNE, low half
    ub = (ub + 0x7FFFu + ((ub >> 16) & 1u)) & 0xFFFF0000u;  // RNE, high half
    return ua | ub;
}

// ---------------- kernel 0: weight prep ----------------
__global__ __launch_bounds__(256) void prep_kernel(
    const float* __restrict__ Wqkv, const float* __restrict__ W1,
    const float* __restrict__ W2, float* __restrict__ Wq1,
    float* __restrict__ Wk1, float* __restrict__ W2T)
{
    const int tid = threadIdx.x;
    for (int i = tid; i < 2048; i += 256) {
        const int d = i >> 5, c = i & 31;
        float aq = 0.f, ak = 0.f;
#pragma unroll
        for (int k = 0; k < 32; ++k) {
            const float w1 = W1[d * 32 + k];
            aq = fmaf(w1, Wqkv[k * 32 + c], aq);
            ak = fmaf(w1, Wqkv[(32 + k) * 32 + c], ak);
        }
        Wq1[i] = aq;
        Wk1[i] = ak;
        W2T[i] = W2[c * 64 + d];
    }
}

// ---------------- kernel 1: projections (bf16 pixel-major) + gate/residual ----------------
__global__ __launch_bounds__(256) void kv_kernel(
    const float* __restrict__ x, const float* __restrict__ Wqkv,
    const float* __restrict__ Wk1, const float* __restrict__ Wq1,
    const float* __restrict__ b1, const float* __restrict__ Wg,
    const float* __restrict__ bg, unsigned* __restrict__ khg,
    unsigned* __restrict__ qhg, unsigned* __restrict__ vg,
    float* __restrict__ out)
{
    const int pix = blockIdx.x * 256 + threadIdx.x;
    const int b = pix >> 16;
    const int rem = pix & 65535;

    const float* xp = x + (size_t)b * (32 * HWm) + rem;
    float xv[32];
#pragma unroll
    for (int c = 0; c < 32; ++c) xv[c] = xp[c * HWm];

    // kh = Wk1 @ x -> bf16 pixel-major (32 words = 8 uint4 per px)
    uint4* khp = (uint4*)khg + (size_t)pix * 8;
    for (int g = 0; g < 8; ++g) {
        float a[8];
#pragma unroll
        for (int j = 0; j < 8; ++j) {
            const float* wr = Wk1 + (g * 8 + j) * 32;
            float acc = 0.f;
#pragma unroll
            for (int c = 0; c < 32; ++c) acc = fmaf(wr[c], xv[c], acc);
            a[j] = acc;
        }
        uint4 u;
        u.x = packbf2(a[0], a[1]); u.y = packbf2(a[2], a[3]);
        u.z = packbf2(a[4], a[5]); u.w = packbf2(a[6], a[7]);
        khp[g] = u;
    }

    // qh = Wq1 @ x + b1 -> bf16 pixel-major
    uint4* qhp = (uint4*)qhg + (size_t)pix * 8;
    for (int g = 0; g < 8; ++g) {
        float a[8];
#pragma unroll
        for (int j = 0; j < 8; ++j) {
            const int d = g * 8 + j;
            const float* wr = Wq1 + d * 32;
            float acc = b1[d];
#pragma unroll
            for (int c = 0; c < 32; ++c) acc = fmaf(wr[c], xv[c], acc);
            a[j] = acc;
        }
        uint4 u;
        u.x = packbf2(a[0], a[1]); u.y = packbf2(a[2], a[3]);
        u.z = packbf2(a[4], a[5]); u.w = packbf2(a[6], a[7]);
        qhp[g] = u;
    }

    // v = Wqkv[64:96] @ x -> bf16 pixel-major (16 words = 4 uint4)
    uint4* vp = (uint4*)vg + (size_t)pix * 4;
    for (int g = 0; g < 4; ++g) {
        float a[8];
#pragma unroll
        for (int j = 0; j < 8; ++j) {
            const float* wr = Wqkv + (64 + g * 8 + j) * 32;
            float acc = 0.f;
#pragma unroll
            for (int c = 0; c < 32; ++c) acc = fmaf(wr[c], xv[c], acc);
            a[j] = acc;
        }
        uint4 u;
        u.x = packbf2(a[0], a[1]); u.y = packbf2(a[2], a[3]);
        u.z = packbf2(a[4], a[5]); u.w = packbf2(a[6], a[7]);
        vp[g] = u;
    }

    // out = Wg @ x + bg + x   (attn adds the rest)
    float* outp = out + (size_t)b * (32 * HWm) + rem;
#pragma unroll 4
    for (int c = 0; c < 32; ++c) {
        float acc = bg[c];
        const float* wr = Wg + c * 32;
#pragma unroll
        for (int k = 0; k < 32; ++k) acc = fmaf(wr[k], xv[k], acc);
        outp[c * HWm] = acc + xv[c];
    }
}

// ---------------- kernel 2: tiled attention, LDS halo ----------------
// tile 16x16, halo 18x18=324 px. kh: 32 words padded to 36 (144B=9x16B, odd multiple
// of 16B -> conflict-free b128 reads). v: 16 words padded to 20 (80B=5x16B).
__global__ __launch_bounds__(256, 2) void attn_kernel(
    const unsigned* __restrict__ qhg, const unsigned* __restrict__ khg,
    const unsigned* __restrict__ vg, const float* __restrict__ W2T,
    const float* __restrict__ lnw, const float* __restrict__ lnb,
    const float* __restrict__ b2, float* __restrict__ out)
{
    __shared__ __align__(16) unsigned khL[324 * 36];  // 46656 B
    __shared__ __align__(16) unsigned vL[324 * 20];   // 25920 B

    const int tid = threadIdx.x;
    // XCD swizzle: 1024 blocks % 8 == 0 -> bijective; each XCD gets a 128-row band
    const int bid = blockIdx.x;
    const int swz = (bid & 7) * 128 + (bid >> 3);
    const int b = swz >> 8;
    const int trem = swz & 255;
    const int h0 = (trem >> 4) << 4;
    const int w0 = (trem & 15) << 4;

    // ---- stage kh halo (2592 x 16B chunks) ----
    const uint4* khg4 = (const uint4*)khg;
    for (int c = tid; c < 2592; c += 256) {
        const int hp = c >> 3, slot = c & 7;
        const int hy = hp / 18;
        const int hx = hp - hy * 18;
        const int gh = h0 - 1 + hy, gw = w0 - 1 + hx;
        const bool valid = ((unsigned)gh < 256u) && ((unsigned)gw < 256u);
        const int gpx = (b << 16) + ((valid ? gh : 0) << 8) + (valid ? gw : 0);
        uint4 val = khg4[(size_t)gpx * 8 + slot];
        if (!valid) { val.x = 0u; val.y = 0u; val.z = 0u; val.w = 0u; }
        *(uint4*)&khL[hp * 36 + slot * 4] = val;
    }
    // ---- stage v halo (1296 x 16B chunks) ----
    const uint4* vg4 = (const uint4*)vg;
    for (int c = tid; c < 1296; c += 256) {
        const int hp = c >> 2, slot = c & 3;
        const int hy = hp / 18;
        const int hx = hp - hy * 18;
        const int gh = h0 - 1 + hy, gw = w0 - 1 + hx;
        const bool valid = ((unsigned)gh < 256u) && ((unsigned)gw < 256u);
        const int gpx = (b << 16) + ((valid ? gh : 0) << 8) + (valid ? gw : 0);
        uint4 val = vg4[(size_t)gpx * 4 + slot];
        if (!valid) { val.x = 0u; val.y = 0u; val.z = 0u; val.w = 0u; }
        *(uint4*)&vL[hp * 20 + slot * 4] = val;
    }
    __syncthreads();

    const int tx = tid & 15, ty = tid >> 4;
    const int pix = (b << 16) + ((h0 + ty) << 8) + (w0 + tx);
    const int hbase = (ty + 1) * 18 + (tx + 1);

    // qh for own pixel (bf16 -> f32 regs)
    float qh[64];
    {
        const uint4* qp = (const uint4*)qhg + (size_t)pix * 8;
#pragma unroll
        for (int i = 0; i < 8; ++i) {
            const uint4 u = qp[i];
            qh[i * 8 + 0] = bflo(u.x); qh[i * 8 + 1] = bfhi(u.x);
            qh[i * 8 + 2] = bflo(u.y); qh[i * 8 + 3] = bfhi(u.y);
            qh[i * 8 + 4] = bflo(u.z); qh[i * 8 + 5] = bfhi(u.z);
            qh[i * 8 + 6] = bflo(u.w); qh[i * 8 + 7] = bfhi(u.w);
        }
    }

    float ssum[32], wv[32];
#pragma unroll
    for (int c = 0; c < 32; ++c) { ssum[c] = 0.f; wv[c] = 0.f; }

    for (int n = 0; n < 9; ++n) {
        const int dy = n / 3;
        const int dx = n - dy * 3;
        const int hp = hbase + dy * 18 + dx - 19;

        // kh vector for this neighbor from LDS (stays in regs for both passes)
        unsigned kw[32];
        {
            const uint4* kr = (const uint4*)&khL[hp * 36];
#pragma unroll
            for (int i = 0; i < 8; ++i) {
                const uint4 t = kr[i];
                kw[i * 4 + 0] = t.x; kw[i * 4 + 1] = t.y;
                kw[i * 4 + 2] = t.z; kw[i * 4 + 3] = t.w;
            }
        }

        // pass 1: LN stats of hid = qh - kh
        float sum = 0.f, sumsq = 0.f;
#pragma unroll
        for (int i = 0; i < 32; ++i) {
            const float a0 = qh[2 * i]     - bflo(kw[i]);
            const float a1 = qh[2 * i + 1] - bfhi(kw[i]);
            sum += a0 + a1;
            sumsq = fmaf(a0, a0, sumsq);
            sumsq = fmaf(a1, a1, sumsq);
        }
        const float mean = sum * 0.015625f;
        float var = fmaf(-mean, mean, sumsq * 0.015625f);
        var = fmaxf(var, 0.f);
        const float inv = 1.f / (sqrtf(var) + 1e-5f);

        // pass 2: scores = W2 @ relu(LN(hid)) + b2
        float sc[32];
#pragma unroll
        for (int c = 0; c < 32; ++c) sc[c] = b2[c];
#pragma unroll 8
        for (int i = 0; i < 32; ++i) {
            float hn0 = (qh[2 * i]     - bflo(kw[i]) - mean) * inv;
            float hn1 = (qh[2 * i + 1] - bfhi(kw[i]) - mean) * inv;
            hn0 = fmaxf(fmaf(hn0, lnw[2 * i],     lnb[2 * i]),     0.f);
            hn1 = fmaxf(fmaf(hn1, lnw[2 * i + 1], lnb[2 * i + 1]), 0.f);
            const float* w2a = W2T + 64 * i;  // rows 2i, 2i+1
#pragma unroll
            for (int c = 0; c < 32; ++c) sc[c] = fmaf(w2a[c], hn0, sc[c]);
#pragma unroll
            for (int c = 0; c < 32; ++c) sc[c] = fmaf(w2a[32 + c], hn1, sc[c]);
        }

        // pass 3: online softmax accumulate with v from LDS
        const uint4* vr = (const uint4*)&vL[hp * 20];
#pragma unroll
        for (int i = 0; i < 4; ++i) {
            const uint4 t = vr[i];
            const unsigned w4[4] = { t.x, t.y, t.z, t.w };
#pragma unroll
            for (int j = 0; j < 4; ++j) {
                const int c = i * 8 + j * 2;
                const float e0 = __expf(sc[c]);
                const float e1 = __expf(sc[c + 1]);
                ssum[c]     += e0;
                ssum[c + 1] += e1;
                wv[c]     = fmaf(e0, bflo(w4[j]), wv[c]);
                wv[c + 1] = fmaf(e1, bfhi(w4[j]), wv[c + 1]);
            }
        }
    }

    float* outp = out + (size_t)b * (32 * HWm) + ((h0 + ty) << 8) + (w0 + tx);
#pragma unroll
    for (int c = 0; c < 32; ++c) {
        outp[c * HWm] += wv[c] / ssum[c];
    }
}

extern "C" void kernel_launch(void* const* d_in, const int* in_sizes, int n_in,
                              void* d_out, int out_size, void* d_ws, size_t ws_size,
                              hipStream_t stream) {
    const float* x    = (const float*)d_in[0];
    const float* Wqkv = (const float*)d_in[1];
    const float* W1   = (const float*)d_in[2];
    const float* b1   = (const float*)d_in[3];
    const float* lnw  = (const float*)d_in[4];
    const float* lnb  = (const float*)d_in[5];
    const float* W2   = (const float*)d_in[6];
    const float* b2   = (const float*)d_in[7];
    const float* Wg   = (const float*)d_in[8];
    const float* bg   = (const float*)d_in[9];
    float* out = (float*)d_out;

    float* ws  = (float*)d_ws;
    float* Wq1 = ws;                         // 2048 f32
    float* Wk1 = ws + 2048;                  // 2048 f32
    float* W2T = ws + 4096;                  // 2048 f32
    unsigned* khg = (unsigned*)(ws + 6144);          // 64ch bf16 = 8 uint4/px
    unsigned* qhg = khg + 8388608;                   // 33.5 MB later
    unsigned* vg  = qhg + 8388608;                   // 32ch bf16 = 4 uint4/px

    const int nblocks = NPIX / 256;  // 1024
    prep_kernel<<<1, 256, 0, stream>>>(Wqkv, W1, W2, Wq1, Wk1, W2T);
    kv_kernel<<<nblocks, 256, 0, stream>>>(x, Wqkv, Wk1, Wq1, b1, Wg, bg,
                                           khg, qhg, vg, out);
    attn_kernel<<<nblocks, 256, 0, stream>>>(qhg, khg, vg, W2T, lnw, lnb, b2, out);
}

// Round 5
// 209.233 us; speedup vs baseline: 2.9110x; 1.6172x over previous
//
#include <hip/hip_runtime.h>

// VectorAttention: B=4, C=32, H=256, W=256, HID=64, all fp32 in/out.
// hid_n = (Wq1@x + b1) - (Wk1@x)|neighbor ; scores = W2@relu(LN(hid)) via MFMA
// ws (floats): [0,2048) Wq1 | [2048,4096) Wk1 | [4096,5120) W2A (1024 u32, bf16 A-frags)
//              khg: NPIX*32 u32 (64ch bf16/px) | qhg same | vg: NPIX*16 u32 (32ch bf16/px)

#define HWm 65536
#define NPIX 262144

typedef __attribute__((ext_vector_type(8))) short short8;
typedef __attribute__((ext_vector_type(4))) float f32x4;

__device__ __forceinline__ float bflo(unsigned u) { return __uint_as_float(u << 16); }
__device__ __forceinline__ float bfhi(unsigned u) { return __uint_as_float(u & 0xFFFF0000u); }
__device__ __forceinline__ unsigned packbf2(float a, float b) {
    unsigned ua = __float_as_uint(a);
    unsigned ub = __float_as_uint(b);
    ua = (ua + 0x7FFFu + ((ua >> 16) & 1u)) >> 16;          // RNE
    ub = (ub + 0x7FFFu + ((ub >> 16) & 1u)) & 0xFFFF0000u;  // RNE
    return ua | ub;
}
__device__ __forceinline__ unsigned cvtpk(float lo, float hi) {
    unsigned r;
    asm("v_cvt_pk_bf16_f32 %0, %1, %2" : "=v"(r) : "v"(lo), "v"(hi));
    return r;
}

// ---------------- kernel 0: weight prep ----------------
__global__ __launch_bounds__(256) void prep_kernel(
    const float* __restrict__ Wqkv, const float* __restrict__ W1,
    const float* __restrict__ W2, float* __restrict__ Wq1,
    float* __restrict__ Wk1, unsigned* __restrict__ W2A)
{
    const int tid = threadIdx.x;
    for (int i = tid; i < 2048; i += 256) {
        const int d = i >> 5, c = i & 31;
        float aq = 0.f, ak = 0.f;
#pragma unroll
        for (int k = 0; k < 32; ++k) {
            const float w1 = W1[d * 32 + k];
            aq = fmaf(w1, Wqkv[k * 32 + c], aq);
            ak = fmaf(w1, Wqkv[(32 + k) * 32 + c], ak);
        }
        Wq1[i] = aq;
        Wk1[i] = ak;
    }
    // W2 A-fragments, bf16: frag (ct, kb), lane l, elem j -> W2[(l&15)+16ct][kb*32+(l>>4)*8+j]
    for (int i = tid; i < 1024; i += 256) {
        const int w = i & 3;
        const int lane = (i >> 2) & 63;
        const int kb = (i >> 8) & 1;
        const int ct = (i >> 9) & 1;
        const int row = (lane & 15) + 16 * ct;
        const int k0 = kb * 32 + ((lane >> 4) & 3) * 8 + 2 * w;
        W2A[i] = packbf2(W2[row * 64 + k0], W2[row * 64 + k0 + 1]);
    }
}

// ---------------- kernel 1: projections (bf16 pixel-major) + gate/residual ----------------
__global__ __launch_bounds__(256) void kv_kernel(
    const float* __restrict__ x, const float* __restrict__ Wqkv,
    const float* __restrict__ Wk1, const float* __restrict__ Wq1,
    const float* __restrict__ b1, const float* __restrict__ Wg,
    const float* __restrict__ bg, unsigned* __restrict__ khg,
    unsigned* __restrict__ qhg, unsigned* __restrict__ vg,
    float* __restrict__ out)
{
    const int pix = blockIdx.x * 256 + threadIdx.x;
    const int b = pix >> 16;
    const int rem = pix & 65535;

    const float* xp = x + (size_t)b * (32 * HWm) + rem;
    float xv[32];
#pragma unroll
    for (int c = 0; c < 32; ++c) xv[c] = xp[c * HWm];

    uint4* khp = (uint4*)khg + (size_t)pix * 8;
    for (int g = 0; g < 8; ++g) {
        float a[8];
#pragma unroll
        for (int j = 0; j < 8; ++j) {
            const float* wr = Wk1 + (g * 8 + j) * 32;
            float acc = 0.f;
#pragma unroll
            for (int c = 0; c < 32; ++c) acc = fmaf(wr[c], xv[c], acc);
            a[j] = acc;
        }
        uint4 u;
        u.x = cvtpk(a[0], a[1]); u.y = cvtpk(a[2], a[3]);
        u.z = cvtpk(a[4], a[5]); u.w = cvtpk(a[6], a[7]);
        khp[g] = u;
    }

    uint4* qhp = (uint4*)qhg + (size_t)pix * 8;
    for (int g = 0; g < 8; ++g) {
        float a[8];
#pragma unroll
        for (int j = 0; j < 8; ++j) {
            const int d = g * 8 + j;
            const float* wr = Wq1 + d * 32;
            float acc = b1[d];
#pragma unroll
            for (int c = 0; c < 32; ++c) acc = fmaf(wr[c], xv[c], acc);
            a[j] = acc;
        }
        uint4 u;
        u.x = cvtpk(a[0], a[1]); u.y = cvtpk(a[2], a[3]);
        u.z = cvtpk(a[4], a[5]); u.w = cvtpk(a[6], a[7]);
        qhp[g] = u;
    }

    uint4* vp = (uint4*)vg + (size_t)pix * 4;
    for (int g = 0; g < 4; ++g) {
        float a[8];
#pragma unroll
        for (int j = 0; j < 8; ++j) {
            const float* wr = Wqkv + (64 + g * 8 + j) * 32;
            float acc = 0.f;
#pragma unroll
            for (int c = 0; c < 32; ++c) acc = fmaf(wr[c], xv[c], acc);
            a[j] = acc;
        }
        uint4 u;
        u.x = cvtpk(a[0], a[1]); u.y = cvtpk(a[2], a[3]);
        u.z = cvtpk(a[4], a[5]); u.w = cvtpk(a[6], a[7]);
        vp[g] = u;
    }

    float* outp = out + (size_t)b * (32 * HWm) + rem;
#pragma unroll 4
    for (int c = 0; c < 32; ++c) {
        float acc = bg[c];
        const float* wr = Wg + c * 32;
#pragma unroll
        for (int k = 0; k < 32; ++k) acc = fmaf(wr[k], xv[k], acc);
        outp[c * HWm] = acc + xv[c];
    }
}

// ---------------- kernel 2: MFMA attention ----------------
// 16x16 px tile / block, 4 waves. Wave w owns tile rows 4w..4w+3 (its own 64 threads'
// pixels) for both hid-compute and MFMA -> zero barriers. hidL: [px][64 k] bf16,
// 16B chunks XOR-swizzled by ((px&7)<<4).
__global__ __launch_bounds__(256) void attn_kernel(
    const unsigned* __restrict__ qhg, const unsigned* __restrict__ khg,
    const unsigned* __restrict__ vg, const short8* __restrict__ w2a,
    const float* __restrict__ lnw, const float* __restrict__ lnb,
    const float* __restrict__ b2, float* __restrict__ out)
{
    __shared__ __align__(16) char hidL[32768];

    const int tid = threadIdx.x;
    const int bid = blockIdx.x;
    const int swz = (bid & 7) * 128 + (bid >> 3);
    const int b = swz >> 8;
    const int trem = swz & 255;
    const int h0 = (trem >> 4) << 4;
    const int w0 = (trem & 15) << 4;

    const int l = tid & 63;
    const int lane15 = tid & 15;
    const int q = (tid >> 4) & 3;
    const int wrow = tid >> 6;

    const int row = tid >> 4;               // own pixel tile row
    const int h = h0 + row, w = w0 + lane15;
    const int pix = (b << 16) + (h << 8) + w;

    // own-pixel qh, packed bf16
    unsigned qw[32];
    {
        const uint4* qp = (const uint4*)qhg + (size_t)pix * 8;
#pragma unroll
        for (int i = 0; i < 8; ++i) {
            const uint4 u = qp[i];
            qw[4 * i] = u.x; qw[4 * i + 1] = u.y; qw[4 * i + 2] = u.z; qw[4 * i + 3] = u.w;
        }
    }

    // A fragments (W2), persistent
    const short8 a00 = w2a[0 * 64 + l];
    const short8 a01 = w2a[1 * 64 + l];
    const short8 a10 = w2a[2 * 64 + l];
    const short8 a11 = w2a[3 * 64 + l];

    // b2 for this lane's 8 channels
    float b2v[8];
    {
        const float4 t0 = *(const float4*)(b2 + q * 4);
        const float4 t1 = *(const float4*)(b2 + 16 + q * 4);
        b2v[0] = t0.x; b2v[1] = t0.y; b2v[2] = t0.z; b2v[3] = t0.w;
        b2v[4] = t1.x; b2v[5] = t1.y; b2v[6] = t1.z; b2v[7] = t1.w;
    }

    float ssum[32], wv[32];
#pragma unroll
    for (int i = 0; i < 32; ++i) { ssum[i] = 0.f; wv[i] = 0.f; }

    const uint4* khg4 = (const uint4*)khg;
    char* const myhid = hidL + tid * 128;
    const int myswz = (tid & 7) << 4;

    for (int n = 0; n < 9; ++n) {
        const int dy = n / 3 - 1, dx = n % 3 - 1;

        // ---- pass 1: pre-LN hid -> LDS (bf16) + LN stats ----
        float sum = 0.f, sumsq = 0.f;
        {
            const int hh = h + dy, ww = w + dx;
            const bool valid = ((unsigned)hh < 256u) && ((unsigned)ww < 256u);
            const int np = (b << 16) + ((valid ? hh : 0) << 8) + (valid ? ww : 0);
            const uint4* kp = khg4 + (size_t)np * 8;
#pragma unroll
            for (int cj = 0; cj < 8; ++cj) {
                uint4 kc = kp[cj];
                const unsigned k0 = valid ? kc.x : 0u, k1 = valid ? kc.y : 0u;
                const unsigned k2 = valid ? kc.z : 0u, k3 = valid ? kc.w : 0u;
                float hd[8];
                hd[0] = bflo(qw[cj * 4 + 0]) - bflo(k0);
                hd[1] = bfhi(qw[cj * 4 + 0]) - bfhi(k0);
                hd[2] = bflo(qw[cj * 4 + 1]) - bflo(k1);
                hd[3] = bfhi(qw[cj * 4 + 1]) - bfhi(k1);
                hd[4] = bflo(qw[cj * 4 + 2]) - bflo(k2);
                hd[5] = bfhi(qw[cj * 4 + 2]) - bfhi(k2);
                hd[6] = bflo(qw[cj * 4 + 3]) - bflo(k3);
                hd[7] = bfhi(qw[cj * 4 + 3]) - bfhi(k3);
#pragma unroll
                for (int j = 0; j < 8; ++j) {
                    sum += hd[j];
                    sumsq = fmaf(hd[j], hd[j], sumsq);
                }
                uint4 o;
                o.x = cvtpk(hd[0], hd[1]); o.y = cvtpk(hd[2], hd[3]);
                o.z = cvtpk(hd[4], hd[5]); o.w = cvtpk(hd[6], hd[7]);
                *(uint4*)(myhid + ((cj * 16) ^ myswz)) = o;
            }
        }
        const float mean = sum * 0.015625f;
        float var = fmaf(-mean, mean, sumsq * 0.015625f);
        var = fmaxf(var, 0.f);
        const float inv = 1.f / (sqrtf(var) + 1e-5f);
        const float nmi = -mean * inv;

        // ---- pass 2: RMW normalize+relu in LDS ----
#pragma unroll
        for (int cj = 0; cj < 8; ++cj) {
            char* p = myhid + ((cj * 16) ^ myswz);
            const uint4 t = *(const uint4*)p;
            float hv[8];
            hv[0] = bflo(t.x); hv[1] = bfhi(t.x);
            hv[2] = bflo(t.y); hv[3] = bfhi(t.y);
            hv[4] = bflo(t.z); hv[5] = bfhi(t.z);
            hv[6] = bflo(t.w); hv[7] = bfhi(t.w);
#pragma unroll
            for (int j = 0; j < 8; ++j) {
                float tv = fmaf(hv[j], inv, nmi);
                tv = fmaf(tv, lnw[cj * 8 + j], lnb[cj * 8 + j]);
                hv[j] = fmaxf(tv, 0.f);
            }
            uint4 o;
            o.x = cvtpk(hv[0], hv[1]); o.y = cvtpk(hv[2], hv[3]);
            o.z = cvtpk(hv[4], hv[5]); o.w = cvtpk(hv[6], hv[7]);
            *(uint4*)p = o;
        }

        // ---- MFMA + softmax accumulate (wave-local rows) ----
#pragma unroll
        for (int gg = 0; gg < 4; ++gg) {
            const int g = wrow * 4 + gg;
            const int px = g * 16 + lane15;
            const char* bp = hidL + px * 128;
            const int sw = (lane15 & 7) << 4;
            const short8 b0 = *(const short8*)(bp + ((q * 16) ^ sw));
            const short8 b1 = *(const short8*)(bp + (((4 + q) * 16) ^ sw));
            f32x4 acc0 = { b2v[0], b2v[1], b2v[2], b2v[3] };
            f32x4 acc1 = { b2v[4], b2v[5], b2v[6], b2v[7] };
            acc0 = __builtin_amdgcn_mfma_f32_16x16x32_bf16(a00, b0, acc0, 0, 0, 0);
            acc0 = __builtin_amdgcn_mfma_f32_16x16x32_bf16(a01, b1, acc0, 0, 0, 0);
            acc1 = __builtin_amdgcn_mfma_f32_16x16x32_bf16(a10, b0, acc1, 0, 0, 0);
            acc1 = __builtin_amdgcn_mfma_f32_16x16x32_bf16(a11, b1, acc1, 0, 0, 0);

            const int gh = h0 + g + dy, gw = w0 + lane15 + dx;
            const bool vld = ((unsigned)gh < 256u) && ((unsigned)gw < 256u);
            const int np = (b << 16) + ((vld ? gh : 0) << 8) + (vld ? gw : 0);
            const unsigned* vp = vg + (size_t)np * 16;
            uint2 vA = *(const uint2*)(vp + q * 2);
            uint2 vB = *(const uint2*)(vp + 8 + q * 2);
            if (!vld) { vA.x = 0u; vA.y = 0u; vB.x = 0u; vB.y = 0u; }
            const float va[4] = { bflo(vA.x), bfhi(vA.x), bflo(vA.y), bfhi(vA.y) };
            const float vb[4] = { bflo(vB.x), bfhi(vB.x), bflo(vB.y), bfhi(vB.y) };
#pragma unroll
            for (int r = 0; r < 4; ++r) {
                const float e0 = __expf(acc0[r]);
                ssum[gg * 8 + r] += e0;
                wv[gg * 8 + r] = fmaf(e0, va[r], wv[gg * 8 + r]);
                const float e1 = __expf(acc1[r]);
                ssum[gg * 8 + 4 + r] += e1;
                wv[gg * 8 + 4 + r] = fmaf(e1, vb[r], wv[gg * 8 + 4 + r]);
            }
        }
    }

    // ---- output RMW: out += softmax-weighted v ----
#pragma unroll
    for (int gg = 0; gg < 4; ++gg) {
        const int g = wrow * 4 + gg;
        float* op = out + (size_t)b * (32 * HWm) + ((h0 + g) << 8) + (w0 + lane15);
#pragma unroll
        for (int r = 0; r < 4; ++r) {
            const int ch0 = q * 4 + r;
            const int ch1 = 16 + q * 4 + r;
            op[ch0 * HWm] += wv[gg * 8 + r] / ssum[gg * 8 + r];
            op[ch1 * HWm] += wv[gg * 8 + 4 + r] / ssum[gg * 8 + 4 + r];
        }
    }
}

extern "C" void kernel_launch(void* const* d_in, const int* in_sizes, int n_in,
                              void* d_out, int out_size, void* d_ws, size_t ws_size,
                              hipStream_t stream) {
    const float* x    = (const float*)d_in[0];
    const float* Wqkv = (const float*)d_in[1];
    const float* W1   = (const float*)d_in[2];
    const float* b1   = (const float*)d_in[3];
    const float* lnw  = (const float*)d_in[4];
    const float* lnb  = (const float*)d_in[5];
    const float* W2   = (const float*)d_in[6];
    const float* b2   = (const float*)d_in[7];
    const float* Wg   = (const float*)d_in[8];
    const float* bg   = (const float*)d_in[9];
    float* out = (float*)d_out;

    float* ws  = (float*)d_ws;
    float* Wq1 = ws;                           // 2048 f32
    float* Wk1 = ws + 2048;                    // 2048 f32
    unsigned* W2A = (unsigned*)(ws + 4096);    // 1024 u32
    unsigned* khg = (unsigned*)(ws + 6144);    // NPIX*32 u32
    unsigned* qhg = khg + (size_t)NPIX * 32;
    unsigned* vg  = qhg + (size_t)NPIX * 32;   // NPIX*16 u32

    const int nblocks = NPIX / 256;  // 1024
    prep_kernel<<<1, 256, 0, stream>>>(Wqkv, W1, W2, Wq1, Wk1, W2A);
    kv_kernel<<<nblocks, 256, 0, stream>>>(x, Wqkv, Wk1, Wq1, b1, Wg, bg,
                                           khg, qhg, vg, out);
    attn_kernel<<<nblocks, 256, 0, stream>>>(qhg, khg, vg, (const short8*)W2A,
                                             lnw, lnb, b2, out);
}

// Round 6
// 207.770 us; speedup vs baseline: 2.9315x; 1.0070x over previous
//
#include <hip/hip_runtime.h>

// VectorAttention: B=4, C=32, H=256, W=256, HID=64, all fp32 in/out.
// hid_n = (Wq1@x + b1) - (Wk1@x)|neighbor ; scores = W2@relu(LN(hid)) via MFMA
// attn: 512-thread blocks, 16x16 tile; waves 0-3 = neighbors 0-3 (buf A),
//       waves 4-7 = neighbors 4-8 (buf B); LDS merge of partial softmax.

#define HWm 65536
#define NPIX 262144

typedef __attribute__((ext_vector_type(8))) short short8;
typedef __attribute__((ext_vector_type(4))) float f32x4;

__device__ __forceinline__ float bflo(unsigned u) { return __uint_as_float(u << 16); }
__device__ __forceinline__ float bfhi(unsigned u) { return __uint_as_float(u & 0xFFFF0000u); }
__device__ __forceinline__ unsigned packbf2(float a, float b) {
    unsigned ua = __float_as_uint(a);
    unsigned ub = __float_as_uint(b);
    ua = (ua + 0x7FFFu + ((ua >> 16) & 1u)) >> 16;          // RNE
    ub = (ub + 0x7FFFu + ((ub >> 16) & 1u)) & 0xFFFF0000u;  // RNE
    return ua | ub;
}
__device__ __forceinline__ unsigned cvtpk(float lo, float hi) {
    unsigned r;
    asm("v_cvt_pk_bf16_f32 %0, %1, %2" : "=v"(r) : "v"(lo), "v"(hi));
    return r;
}

// ---------------- kernel 0: weight prep ----------------
__global__ __launch_bounds__(256) void prep_kernel(
    const float* __restrict__ Wqkv, const float* __restrict__ W1,
    const float* __restrict__ W2, float* __restrict__ Wq1,
    float* __restrict__ Wk1, unsigned* __restrict__ W2A)
{
    const int tid = threadIdx.x;
    for (int i = tid; i < 2048; i += 256) {
        const int d = i >> 5, c = i & 31;
        float aq = 0.f, ak = 0.f;
#pragma unroll
        for (int k = 0; k < 32; ++k) {
            const float w1 = W1[d * 32 + k];
            aq = fmaf(w1, Wqkv[k * 32 + c], aq);
            ak = fmaf(w1, Wqkv[(32 + k) * 32 + c], ak);
        }
        Wq1[i] = aq;
        Wk1[i] = ak;
    }
    // W2 A-fragments, bf16: frag (ct, kb), lane l, elem j -> W2[(l&15)+16ct][kb*32+(l>>4)*8+j]
    for (int i = tid; i < 1024; i += 256) {
        const int w = i & 3;
        const int lane = (i >> 2) & 63;
        const int kb = (i >> 8) & 1;
        const int ct = (i >> 9) & 1;
        const int row = (lane & 15) + 16 * ct;
        const int k0 = kb * 32 + ((lane >> 4) & 3) * 8 + 2 * w;
        W2A[i] = packbf2(W2[row * 64 + k0], W2[row * 64 + k0 + 1]);
    }
}

// ---------------- kernel 1: projections (bf16 pixel-major) + gate/residual ----------------
__global__ __launch_bounds__(256) void kv_kernel(
    const float* __restrict__ x, const float* __restrict__ Wqkv,
    const float* __restrict__ Wk1, const float* __restrict__ Wq1,
    const float* __restrict__ b1, const float* __restrict__ Wg,
    const float* __restrict__ bg, unsigned* __restrict__ khg,
    unsigned* __restrict__ qhg, unsigned* __restrict__ vg,
    float* __restrict__ out)
{
    const int pix = blockIdx.x * 256 + threadIdx.x;
    const int b = pix >> 16;
    const int rem = pix & 65535;

    const float* xp = x + (size_t)b * (32 * HWm) + rem;
    float xv[32];
#pragma unroll
    for (int c = 0; c < 32; ++c) xv[c] = xp[c * HWm];

    uint4* khp = (uint4*)khg + (size_t)pix * 8;
    for (int g = 0; g < 8; ++g) {
        float a[8];
#pragma unroll
        for (int j = 0; j < 8; ++j) {
            const float* wr = Wk1 + (g * 8 + j) * 32;
            float acc = 0.f;
#pragma unroll
            for (int c = 0; c < 32; ++c) acc = fmaf(wr[c], xv[c], acc);
            a[j] = acc;
        }
        uint4 u;
        u.x = cvtpk(a[0], a[1]); u.y = cvtpk(a[2], a[3]);
        u.z = cvtpk(a[4], a[5]); u.w = cvtpk(a[6], a[7]);
        khp[g] = u;
    }

    uint4* qhp = (uint4*)qhg + (size_t)pix * 8;
    for (int g = 0; g < 8; ++g) {
        float a[8];
#pragma unroll
        for (int j = 0; j < 8; ++j) {
            const int d = g * 8 + j;
            const float* wr = Wq1 + d * 32;
            float acc = b1[d];
#pragma unroll
            for (int c = 0; c < 32; ++c) acc = fmaf(wr[c], xv[c], acc);
            a[j] = acc;
        }
        uint4 u;
        u.x = cvtpk(a[0], a[1]); u.y = cvtpk(a[2], a[3]);
        u.z = cvtpk(a[4], a[5]); u.w = cvtpk(a[6], a[7]);
        qhp[g] = u;
    }

    uint4* vp = (uint4*)vg + (size_t)pix * 4;
    for (int g = 0; g < 4; ++g) {
        float a[8];
#pragma unroll
        for (int j = 0; j < 8; ++j) {
            const float* wr = Wqkv + (64 + g * 8 + j) * 32;
            float acc = 0.f;
#pragma unroll
            for (int c = 0; c < 32; ++c) acc = fmaf(wr[c], xv[c], acc);
            a[j] = acc;
        }
        uint4 u;
        u.x = cvtpk(a[0], a[1]); u.y = cvtpk(a[2], a[3]);
        u.z = cvtpk(a[4], a[5]); u.w = cvtpk(a[6], a[7]);
        vp[g] = u;
    }

    float* outp = out + (size_t)b * (32 * HWm) + rem;
#pragma unroll 4
    for (int c = 0; c < 32; ++c) {
        float acc = bg[c];
        const float* wr = Wg + c * 32;
#pragma unroll
        for (int k = 0; k < 32; ++k) acc = fmaf(wr[k], xv[k], acc);
        outp[c * HWm] = acc + xv[c];
    }
}

// ---------------- kernel 2: MFMA attention, neighbor-split across wave groups ----------------
// 16x16 px tile / block of 512 threads. Group g = tid>>8: g=0 handles neighbors 0-3,
// g=1 handles 4-8; same pixel owned by t and t+256. Each group has a private 32KB hid
// buffer (wave-local MFMA, no barriers). Partial (wv,ssum) merged through LDS at end.
__global__ __launch_bounds__(512) void attn_kernel(
    const unsigned* __restrict__ qhg, const unsigned* __restrict__ khg,
    const unsigned* __restrict__ vg, const short8* __restrict__ w2a,
    const float* __restrict__ lnw, const float* __restrict__ lnb,
    const float* __restrict__ b2, float* __restrict__ out)
{
    __shared__ __align__(16) char hidL[65536];  // 2 x 32KB; reused for merge staging

    const int tid = threadIdx.x;
    const int grp = tid >> 8;
    const int p = tid & 255;                 // pixel id within tile

    const int bid = blockIdx.x;
    const int swz = (bid & 7) * 128 + (bid >> 3);
    const int b = swz >> 8;
    const int trem = swz & 255;
    const int h0 = (trem >> 4) << 4;
    const int w0 = (trem & 15) << 4;

    const int l = tid & 63;
    const int lane15 = p & 15;
    const int q = (p >> 4) & 3;
    const int wrow = (p >> 6) & 3;

    const int row = p >> 4;                  // own pixel tile row
    const int h = h0 + row, w = w0 + lane15;
    const int pix = (b << 16) + (h << 8) + w;

    // own-pixel qh, packed bf16
    unsigned qw[32];
    {
        const uint4* qp = (const uint4*)qhg + (size_t)pix * 8;
#pragma unroll
        for (int i = 0; i < 8; ++i) {
            const uint4 u = qp[i];
            qw[4 * i] = u.x; qw[4 * i + 1] = u.y; qw[4 * i + 2] = u.z; qw[4 * i + 3] = u.w;
        }
    }

    // A fragments (W2), persistent
    const short8 a00 = w2a[0 * 64 + l];
    const short8 a01 = w2a[1 * 64 + l];
    const short8 a10 = w2a[2 * 64 + l];
    const short8 a11 = w2a[3 * 64 + l];

    // b2 for this lane's 8 channels
    float b2v[8];
    {
        const float4 t0 = *(const float4*)(b2 + q * 4);
        const float4 t1 = *(const float4*)(b2 + 16 + q * 4);
        b2v[0] = t0.x; b2v[1] = t0.y; b2v[2] = t0.z; b2v[3] = t0.w;
        b2v[4] = t1.x; b2v[5] = t1.y; b2v[6] = t1.z; b2v[7] = t1.w;
    }

    float ssum[32], wv[32];
#pragma unroll
    for (int i = 0; i < 32; ++i) { ssum[i] = 0.f; wv[i] = 0.f; }

    const uint4* khg4 = (const uint4*)khg;
    char* const grpbase = hidL + (grp << 15);
    char* const myhid = grpbase + p * 128;
    const int myswz = (p & 7) << 4;

    const int n_start = grp ? 4 : 0;
    const int n_end = grp ? 9 : 4;

    for (int n = n_start; n < n_end; ++n) {
        const int dy = n / 3 - 1, dx = n % 3 - 1;

        // ---- pass 1: pre-LN hid -> LDS (bf16) + LN stats ----
        float sum = 0.f, sumsq = 0.f;
        {
            const int hh = h + dy, ww = w + dx;
            const bool valid = ((unsigned)hh < 256u) && ((unsigned)ww < 256u);
            const int np = (b << 16) + ((valid ? hh : 0) << 8) + (valid ? ww : 0);
            const uint4* kp = khg4 + (size_t)np * 8;
#pragma unroll
            for (int cj = 0; cj < 8; ++cj) {
                uint4 kc = kp[cj];
                const unsigned k0 = valid ? kc.x : 0u, k1 = valid ? kc.y : 0u;
                const unsigned k2 = valid ? kc.z : 0u, k3 = valid ? kc.w : 0u;
                float hd[8];
                hd[0] = bflo(qw[cj * 4 + 0]) - bflo(k0);
                hd[1] = bfhi(qw[cj * 4 + 0]) - bfhi(k0);
                hd[2] = bflo(qw[cj * 4 + 1]) - bflo(k1);
                hd[3] = bfhi(qw[cj * 4 + 1]) - bfhi(k1);
                hd[4] = bflo(qw[cj * 4 + 2]) - bflo(k2);
                hd[5] = bfhi(qw[cj * 4 + 2]) - bfhi(k2);
                hd[6] = bflo(qw[cj * 4 + 3]) - bflo(k3);
                hd[7] = bfhi(qw[cj * 4 + 3]) - bfhi(k3);
#pragma unroll
                for (int j = 0; j < 8; ++j) {
                    sum += hd[j];
                    sumsq = fmaf(hd[j], hd[j], sumsq);
                }
                uint4 o;
                o.x = cvtpk(hd[0], hd[1]); o.y = cvtpk(hd[2], hd[3]);
                o.z = cvtpk(hd[4], hd[5]); o.w = cvtpk(hd[6], hd[7]);
                *(uint4*)(myhid + ((cj * 16) ^ myswz)) = o;
            }
        }
        const float mean = sum * 0.015625f;
        float var = fmaf(-mean, mean, sumsq * 0.015625f);
        var = fmaxf(var, 0.f);
        const float inv = 1.f / (sqrtf(var) + 1e-5f);
        const float nmi = -mean * inv;

        // ---- pass 2: RMW normalize+relu in LDS ----
#pragma unroll
        for (int cj = 0; cj < 8; ++cj) {
            char* pp = myhid + ((cj * 16) ^ myswz);
            const uint4 t = *(const uint4*)pp;
            float hv[8];
            hv[0] = bflo(t.x); hv[1] = bfhi(t.x);
            hv[2] = bflo(t.y); hv[3] = bfhi(t.y);
            hv[4] = bflo(t.z); hv[5] = bfhi(t.z);
            hv[6] = bflo(t.w); hv[7] = bfhi(t.w);
#pragma unroll
            for (int j = 0; j < 8; ++j) {
                float tv = fmaf(hv[j], inv, nmi);
                tv = fmaf(tv, lnw[cj * 8 + j], lnb[cj * 8 + j]);
                hv[j] = fmaxf(tv, 0.f);
            }
            uint4 o;
            o.x = cvtpk(hv[0], hv[1]); o.y = cvtpk(hv[2], hv[3]);
            o.z = cvtpk(hv[4], hv[5]); o.w = cvtpk(hv[6], hv[7]);
            *(uint4*)pp = o;
        }

        // ---- MFMA + softmax accumulate (wave-local rows within group buffer) ----
#pragma unroll
        for (int gg = 0; gg < 4; ++gg) {
            const int g = wrow * 4 + gg;
            const int px = g * 16 + lane15;
            const char* bp = grpbase + px * 128;
            const int sw = (lane15 & 7) << 4;
            const short8 b0 = *(const short8*)(bp + ((q * 16) ^ sw));
            const short8 b1 = *(const short8*)(bp + (((4 + q) * 16) ^ sw));
            f32x4 acc0 = { b2v[0], b2v[1], b2v[2], b2v[3] };
            f32x4 acc1 = { b2v[4], b2v[5], b2v[6], b2v[7] };
            acc0 = __builtin_amdgcn_mfma_f32_16x16x32_bf16(a00, b0, acc0, 0, 0, 0);
            acc0 = __builtin_amdgcn_mfma_f32_16x16x32_bf16(a01, b1, acc0, 0, 0, 0);
            acc1 = __builtin_amdgcn_mfma_f32_16x16x32_bf16(a10, b0, acc1, 0, 0, 0);
            acc1 = __builtin_amdgcn_mfma_f32_16x16x32_bf16(a11, b1, acc1, 0, 0, 0);

            const int gh = h0 + g + dy, gw = w0 + lane15 + dx;
            const bool vld = ((unsigned)gh < 256u) && ((unsigned)gw < 256u);
            const int np = (b << 16) + ((vld ? gh : 0) << 8) + (vld ? gw : 0);
            const unsigned* vp = vg + (size_t)np * 16;
            uint2 vA = *(const uint2*)(vp + q * 2);
            uint2 vB = *(const uint2*)(vp + 8 + q * 2);
            if (!vld) { vA.x = 0u; vA.y = 0u; vB.x = 0u; vB.y = 0u; }
            const float va[4] = { bflo(vA.x), bfhi(vA.x), bflo(vA.y), bfhi(vA.y) };
            const float vb[4] = { bflo(vB.x), bfhi(vB.x), bflo(vB.y), bfhi(vB.y) };
#pragma unroll
            for (int r = 0; r < 4; ++r) {
                const float e0 = __expf(acc0[r]);
                ssum[gg * 8 + r] += e0;
                wv[gg * 8 + r] = fmaf(e0, va[r], wv[gg * 8 + r]);
                const float e1 = __expf(acc1[r]);
                ssum[gg * 8 + 4 + r] += e1;
                wv[gg * 8 + 4 + r] = fmaf(e1, vb[r], wv[gg * 8 + 4 + r]);
            }
        }
    }

    // ---- merge group B partials into group A, then output RMW ----
    __syncthreads();
    if (grp == 1) {
        // chunk j (16B) of pixel p at hidL + j*4096 + p*16 : conflict-free b128
#pragma unroll
        for (int j = 0; j < 8; ++j) {
            *(float4*)(hidL + j * 4096 + p * 16) =
                make_float4(wv[j * 4], wv[j * 4 + 1], wv[j * 4 + 2], wv[j * 4 + 3]);
        }
#pragma unroll
        for (int j = 0; j < 8; ++j) {
            *(float4*)(hidL + (8 + j) * 4096 + p * 16) =
                make_float4(ssum[j * 4], ssum[j * 4 + 1], ssum[j * 4 + 2], ssum[j * 4 + 3]);
        }
    }
    __syncthreads();
    if (grp == 0) {
#pragma unroll
        for (int j = 0; j < 8; ++j) {
            const float4 t = *(const float4*)(hidL + j * 4096 + p * 16);
            wv[j * 4] += t.x; wv[j * 4 + 1] += t.y; wv[j * 4 + 2] += t.z; wv[j * 4 + 3] += t.w;
        }
#pragma unroll
        for (int j = 0; j < 8; ++j) {
            const float4 t = *(const float4*)(hidL + (8 + j) * 4096 + p * 16);
            ssum[j * 4] += t.x; ssum[j * 4 + 1] += t.y; ssum[j * 4 + 2] += t.z; ssum[j * 4 + 3] += t.w;
        }
#pragma unroll
        for (int gg = 0; gg < 4; ++gg) {
            const int g = wrow * 4 + gg;
            float* op = out + (size_t)b * (32 * HWm) + ((h0 + g) << 8) + (w0 + lane15);
#pragma unroll
            for (int r = 0; r < 4; ++r) {
                const int ch0 = q * 4 + r;
                const int ch1 = 16 + q * 4 + r;
                op[ch0 * HWm] += wv[gg * 8 + r] / ssum[gg * 8 + r];
                op[ch1 * HWm] += wv[gg * 8 + 4 + r] / ssum[gg * 8 + 4 + r];
            }
        }
    }
}

extern "C" void kernel_launch(void* const* d_in, const int* in_sizes, int n_in,
                              void* d_out, int out_size, void* d_ws, size_t ws_size,
                              hipStream_t stream) {
    const float* x    = (const float*)d_in[0];
    const float* Wqkv = (const float*)d_in[1];
    const float* W1   = (const float*)d_in[2];
    const float* b1   = (const float*)d_in[3];
    const float* lnw  = (const float*)d_in[4];
    const float* lnb  = (const float*)d_in[5];
    const float* W2   = (const float*)d_in[6];
    const float* b2   = (const float*)d_in[7];
    const float* Wg   = (const float*)d_in[8];
    const float* bg   = (const float*)d_in[9];
    float* out = (float*)d_out;

    float* ws  = (float*)d_ws;
    float* Wq1 = ws;                           // 2048 f32
    float* Wk1 = ws + 2048;                    // 2048 f32
    unsigned* W2A = (unsigned*)(ws + 4096);    // 1024 u32
    unsigned* khg = (unsigned*)(ws + 6144);    // NPIX*32 u32
    unsigned* qhg = khg + (size_t)NPIX * 32;
    unsigned* vg  = qhg + (size_t)NPIX * 32;   // NPIX*16 u32

    const int nblocks = NPIX / 256;  // 1024
    prep_kernel<<<1, 256, 0, stream>>>(Wqkv, W1, W2, Wq1, Wk1, W2A);
    kv_kernel<<<nblocks, 256, 0, stream>>>(x, Wqkv, Wk1, Wq1, b1, Wg, bg,
                                           khg, qhg, vg, out);
    attn_kernel<<<nblocks, 512, 0, stream>>>(qhg, khg, vg, (const short8*)W2A,
                                             lnw, lnb, b2, out);
}